// Round 7
// baseline (124.194 us; speedup 1.0000x reference)
//
#include <hip/hip_runtime.h>
#include <math.h>

// Problem constants (from reference)
#define N_ELEMS 8000000
#define GL_F       0.1f
#define EL_F       -5.0f
#define IEXT_F     0.4f
#define CM_F       0.3f
#define INV_CM     (1.0f / 0.3f)
#define INV_DTS    2.0f               // 1/DTS, DTS=0.5
#define COEF       0.4f               // 0.5*(1 - DT/DTS)
#define INV_SQRT3  0.57735026918962576f   // 1/(SIGMA*SQ2) = 1/sqrt(3)
#define SQ2_F      1.41421356237309515f
#define SQ2PI_F    0.7978845608028654f

#define ITER    4                      // chunks per thread (best config)
#define NB      1954                   // ceil(2,000,000 / (256*ITER))
#define STRIDE  (NB * 1024)            // elements between a thread's chunks

typedef float v4f __attribute__((ext_vector_type(4)));
typedef float v2f __attribute__((ext_vector_type(2)));

// limiter: reference where-chain is degenerate (idx1&idx2==False always)
__device__ __forceinline__ float limiter(float a, float b) {
    return fminf(0.5f * fabsf(a + b), 2.0f * fminf(fabsf(a), fabsf(b)));
}

// erf via Abramowitz-Stegun 7.1.26 (|err| <= 1.5e-7), shares e2 = exp(-T^2)
__device__ __forceinline__ float erf_as(float x, float e2) {
    float ax = fabsf(x);
    float t  = __fdividef(1.0f, fmaf(0.3275911f, ax, 1.0f));
    float p  = t * fmaf(t, fmaf(t, fmaf(t, fmaf(t, 1.061405429f, -1.453152027f),
                                        1.421413741f), -0.284496736f), 0.254829592f);
    float e  = 1.0f - p * e2;
    return (x < 0.0f) ? -e : e;
}

// H * (1/tau_m): A*inv_tau + (-sqrt2*dTdt*SQ2PI)*e2/denom
// (tau_m in B cancels against /tau_m in H). __expf is base-e (R2 errata).
__device__ __forceinline__ float Hfun(float V0, float dVdt, float inv_tau) {
    float dv = fmaxf(-V0, -1.0f);          // VT = 0
    float T  = dv * INV_SQRT3;
    float p  = 0.0061f + T * (-1.12f + T * (-0.257f + T * (-0.072f + T * (-0.0117f))));
    float A  = __expf(p);
    float e2 = __expf(-T * T);
    float denom = 1.00000001f + erf_as(T, e2);
    float dTdt  = fminf(-dVdt * INV_SQRT3, 0.0f);
    float Bov   = -SQ2_F * dTdt * SQ2PI_F * __fdividef(e2, denom);  // B / tau_m
    return fmaxf(fmaf(A, inv_tau, Bov), 0.0f);
}

// R14: NO-SHUFFLE window assembly. Ledger: R8 fused-atomic tail +26us
// (reverted); R10/R11 oversubscription +3.6us (reverted); R12 VALU CSE
// neutral (not VALU-bound); R13 plain stores -1us (kept; shifted HBM
// writes out of the kernel window). Remaining symptom: latency-bound
// (VALU ~33%, HBM ~25-30% in-kernel, occupancy 34%).
// This round removes the last dependency-chain stage: each chunk's window
// was built with 6 ds_bpermute (lgkm pipe, issuable only AFTER the chunk's
// vmcnt drain) + divergent lane==0/63 halo loads and exec-mask fixups.
// Instead each thread loads its whole stencil window directly:
//   dwordx4 @ j   (main)
//   dwordx2 @ j-2 (clamped to 0 for j==0; 8B-aligned since j%4==0)
//   dword   @ j+4 (clamped to N-1; value cndmask'd to 0 as before)
// Overlap bytes are L1 hits (neighboring threads' main lines), so
// FETCH_SIZE is unchanged; VMEM issue +~25% (cheap); ds_bpermute count
// drops to 0; no divergent branches left in the body. Semantics are
// bit-identical to R13 (same clamps/selects). Everything else frozen:
// load-all-then-compute, ITER=4, limiter CSE, plain stores, params after
// the load storm. Boundary outputs (j=0, j=N-1, dV ends) are garbage
// here; net_fix0 patches them.
__global__ __launch_bounds__(256) void net_main(
    const float* __restrict__ y, const float* __restrict__ gsyn,
    const float* __restrict__ Isyn_p, float* __restrict__ out,
    float* __restrict__ partials)
{
    const float* ro = y;
    const float* V  = y + N_ELEMS;

    int  j0 = (blockIdx.x * 256 + threadIdx.x) * 4;   // chunk 0

    const bool validLast = (j0 + (ITER - 1) * STRIDE) < N_ELEMS;

    // ---- phase 1: issue ALL loads (ITER chunks x {ro,V} x {main,lo,hi}) ----
    v4f rr[ITER], vv[ITER];
    v2f rl[ITER], vl[ITER];              // window low  (z[j-2], z[j-1])
    float rhi[ITER], vhi[ITER];          // window high (z[j+4])

    #pragma unroll
    for (int c = 0; c < ITER; ++c) {
        const int  j   = j0 + c * STRIDE;
        const bool val = (c < ITER - 1) || validLast;   // c<ITER-1 statically true
        if (val) {
            rr[c] = *(const v4f*)(ro + j);
            vv[c] = *(const v4f*)(V + j);
            const int jl = (j > 0) ? j - 2 : 0;             // 8B-aligned
            rl[c] = *(const v2f*)(ro + jl);
            vl[c] = *(const v2f*)(V + jl);
            const int jh = (j + 4 < N_ELEMS) ? j + 4 : N_ELEMS - 1;
            rhi[c] = ro[jh];
            vhi[c] = V[jh];
        } else {
            rr[c] = (v4f){0, 0, 0, 0};
            vv[c] = (v4f){0, 0, 0, 0};
            rl[c] = (v2f){0, 0};
            vl[c] = (v2f){0, 0};
            rhi[c] = 0.0f;
            vhi[c] = 0.0f;
        }
    }

    // scalar params (consumed only in phase 2 — loaded after the main storm)
    float gs      = gsyn[0];
    float Isyn    = Isyn_p[0];
    float inv_tau = (GL_F + gs) * INV_CM;                   // 1/tau_m
    float c1      = (GL_F * EL_F + IEXT_F + Isyn) * INV_CM; // dVdt = c1 - V/3
    float acc = 0.0f;

    // ---- phase 2: compute + store all chunks ----
    #pragma unroll
    for (int c = 0; c < ITER; ++c) {
        const int  j   = j0 + c * STRIDE;
        const bool val = (c < ITER - 1) || validLast;
        if (val) {
            v4f r4 = rr[c], v4 = vv[c];
            // j==0 (block 0, thread 0, chunk 0): fake z[-1]:=z[0] so j==1's
            // wi_1=0; z[-2] only feeds the discarded j==0 output.
            float rm2 = (j > 0) ? rl[c].x : r4.x;
            float rm1 = (j > 0) ? rl[c].y : r4.x;
            float vm2 = (j > 0) ? vl[c].x : v4.x;
            float vm1 = (j > 0) ? vl[c].y : v4.x;
            float rp1 = (j + 4 < N_ELEMS) ? rhi[c] : 0.0f;
            float vp1 = (j + 4 < N_ELEMS) ? vhi[c] : 0.0f;

            // window z[m-2 .. m+4] for outputs m = j..j+3
            float rz[7] = {rm2, rm1, r4.x, r4.y, r4.z, r4.w, rp1};
            float vz[7] = {vm2, vm1, v4.x, v4.y, v4.z, v4.w, vp1};

            // Limiter CSE: diffs D[i] = z[i+1]-z[i] (i=0..5), limiters
            // L[t] = limiter(D[t+1], D[t]) (t=0..4). Output m=j+k:
            //   -(D[k+1] + COEF*(L[k+1]-L[k]))*INV_DTS   (bit-identical to
            // per-element upd_mid; wi_1(k) == wi(k-1) shared).
            float Dr[6], Dv[6];
            #pragma unroll
            for (int i = 0; i < 6; ++i) {
                Dr[i] = rz[i + 1] - rz[i];
                Dv[i] = vz[i + 1] - vz[i];
            }
            float Lr[5], Lv[5];
            #pragma unroll
            for (int t = 0; t < 5; ++t) {
                Lr[t] = limiter(Dr[t + 1], Dr[t]);
                Lv[t] = limiter(Dv[t + 1], Dv[t]);
            }

            float oro[4], ov[4];
            #pragma unroll
            for (int k = 0; k < 4; ++k) {
                float V0   = vz[2 + k];
                float dVdt = fmaf(-INV_CM * GL_F, V0, c1);
                float Hov  = Hfun(V0, dVdt, inv_tau);   // H/tau
                float srcj = rz[2 + k] * Hov;
                acc += srcj;
                oro[k] = -(Dr[k + 1] + COEF * (Lr[k + 1] - Lr[k])) * INV_DTS - srcj;
                ov[k]  = -(Dv[k + 1] + COEF * (Lv[k + 1] - Lv[k])) * INV_DTS + dVdt;
            }

            // plain stores (R13): out fits in L3; cache absorbs the burst,
            // poison-overwrite kills most writebacks.
            *(v4f*)(out + j)           = (v4f){oro[0], oro[1], oro[2], oro[3]};
            *(v4f*)(out + N_ELEMS + j) = (v4f){ov[0], ov[1], ov[2], ov[3]};
        }
    }

    // block reduction (wave64 shuffle, then cross-wave via LDS)
    #pragma unroll
    for (int off = 32; off > 0; off >>= 1)
        acc += __shfl_down(acc, off);
    __shared__ float sred[4];
    if ((threadIdx.x & 63) == 0) sred[threadIdx.x >> 6] = acc;
    __syncthreads();
    if (threadIdx.x == 0)
        partials[blockIdx.x] = sred[0] + sred[1] + sred[2] + sred[3];
}

// Reduce per-block partials -> firing; patch all boundary outputs:
//   out[0]      = -2*ro[0] + firing           (src[0] := -firing)
//   out[N-1]    = (ro[N-2] + coef*wi_last)*2 - src[N-1]
//   out[N]      = 0                            (dV_dt[0])
//   out[2N-1]   = dVdt[N-1]                    (dV_dt[-1])
__global__ __launch_bounds__(256) void net_fix0(
    const float* __restrict__ y, const float* __restrict__ gsyn,
    const float* __restrict__ Isyn_p, const float* __restrict__ partials,
    int nparts, float* __restrict__ out)
{
    __shared__ float sh[256];
    float a = 0.0f;
    for (int i = threadIdx.x; i < nparts; i += 256)
        a += partials[i];
    sh[threadIdx.x] = a;
    __syncthreads();
    for (int s = 128; s > 0; s >>= 1) {
        if (threadIdx.x < s) sh[threadIdx.x] += sh[threadIdx.x + s];
        __syncthreads();
    }
    if (threadIdx.x == 0) {
        float firing = sh[0];
        out[0] = fmaf(-INV_DTS, y[0], firing);
        out[N_ELEMS] = 0.0f;

        float gs      = gsyn[0];
        float Isyn    = Isyn_p[0];
        float inv_tau = (GL_F + gs) * INV_CM;
        float c1      = (GL_F * EL_F + IEXT_F + Isyn) * INV_CM;

        float rN1 = y[N_ELEMS - 1];
        float rN2 = y[N_ELEMS - 2];
        float rN3 = y[N_ELEMS - 3];
        float VN1 = y[2 * N_ELEMS - 1];
        float dVdtN = fmaf(-INV_CM * GL_F, VN1, c1);
        float srcN  = rN1 * Hfun(VN1, dVdtN, inv_tau);
        float wi    = limiter(rN1 - rN2, rN2 - rN3);
        out[N_ELEMS - 1]     = (rN2 + COEF * wi) * INV_DTS - srcN;
        out[2 * N_ELEMS - 1] = dVdtN;
    }
}

extern "C" void kernel_launch(void* const* d_in, const int* in_sizes, int n_in,
                              void* d_out, int out_size, void* d_ws, size_t ws_size,
                              hipStream_t stream)
{
    // setup_inputs order: t, y, gsyn, Isyn
    const float* y    = (const float*)d_in[1];
    const float* gsyn = (const float*)d_in[2];
    const float* Isyn = (const float*)d_in[3];
    float* out = (float*)d_out;
    float* partials = (float*)d_ws;   // NB floats, fully rewritten each call

    net_main<<<NB, 256, 0, stream>>>(y, gsyn, Isyn, out, partials);
    net_fix0<<<1, 256, 0, stream>>>(y, gsyn, Isyn, partials, NB, out);
}